// Round 1
// baseline (204.448 us; speedup 1.0000x reference)
//
#include <hip/hip_runtime.h>

typedef float          f32x4 __attribute__((ext_vector_type(4)));
typedef short          s16x8 __attribute__((ext_vector_type(8)));
typedef unsigned short u16x4 __attribute__((ext_vector_type(4)));

#define NPIX       12544      // B*nH*nW = 16*28*28
#define OUT_STRIDE 12845056   // 16*112*112*64 elements per stream output

__device__ __forceinline__ unsigned short f2bf(float x) {
    union { float f; unsigned u; } un; un.f = x;
    unsigned r = un.u + 0x7FFFu + ((un.u >> 16) & 1u);  // round-to-nearest-even
    return (unsigned short)(r >> 16);
}

// Repack weights fp32 -> bf16 MFMA B-fragments in d_ws, scaled by 1/16.
// Layout (16B fragment granules): [s][t][ks][nt][lane] ; element e fastest.
// Fragment element (lane,e) = w[t][c = ks*32 + (lane>>4)*8 + e][k = nt*16 + (lane&15)] / 16
__global__ __launch_bounds__(256) void repack_weights(
        const float* __restrict__ w1, const float* __restrict__ w2,
        unsigned short* __restrict__ wf) {
    int gid = blockIdx.x * 256 + threadIdx.x;   // 0..131071
    int e  = gid & 7;
    int l  = (gid >> 3) & 63;
    int nt = (gid >> 9) & 3;
    int ks = (gid >> 11) & 1;
    int t  = (gid >> 12) & 15;
    int s  = (gid >> 16) & 1;
    int c = ks * 32 + (l >> 4) * 8 + e;
    int k = nt * 16 + (l & 15);
    const float* __restrict__ w = s ? w2 : w1;
    wf[gid] = f2bf(w[(t * 64 + c) * 64 + k] * 0.0625f);
}

// Block: 256 threads = 4 waves; 16 block-positions (pixels), one stream.
// Wave `wid` owns k-tile [wid*16, wid*16+16).
__global__ __launch_bounds__(256, 3) void iwht_main(
        const float* __restrict__ trans1, const float* __restrict__ trans2,
        const unsigned short* __restrict__ wf,
        const float* __restrict__ bias1, const float* __restrict__ bias2,
        float* __restrict__ out) {
    // A tile: [t][p][c] bf16, row pitch 144 B (128 data + 16 pad -> conflict-free b128 reads)
    __shared__ char Alds[16 * 16 * 144];   // 36864 B

    const int tid = threadIdx.x;
    const int bid = blockIdx.x;   // 0..783
    const int s   = blockIdx.y;   // stream 0/1

    const float* __restrict__ trans = s ? trans2 : trans1;
    const float* __restrict__ bias  = s ? bias2  : bias1;
    const int p0 = bid * 16;

    // ---------------- stage A: global fp32 -> bf16 LDS ----------------
    {
        const int p  = tid >> 4;    // 0..15
        const int cc = tid & 15;    // 4-float chunk of the 64-c row
        f32x4 v[16];
        #pragma unroll
        for (int t = 0; t < 16; ++t) {
            const f32x4* src = (const f32x4*)(trans + ((size_t)t * NPIX + p0) * 64);
            v[t] = src[tid];        // 4 KB fully-coalesced per t
        }
        #pragma unroll
        for (int t = 0; t < 16; ++t) {
            u16x4 h;
            h[0] = f2bf(v[t][0]); h[1] = f2bf(v[t][1]);
            h[2] = f2bf(v[t][2]); h[3] = f2bf(v[t][3]);
            *(u16x4*)(Alds + (t * 16 + p) * 144 + cc * 8) = h;
        }
    }
    __syncthreads();

    const int wid  = tid >> 6;    // n-tile (k quarter)
    const int lane = tid & 63;
    const int lrow = lane & 15;
    const int lhi  = lane >> 4;

    const s16x8* __restrict__ wb = (const s16x8*)wf;

    // out[i][j]: 16 accumulator tiles (16p x 16k each, 4 f32/lane)
    f32x4 o[4][4];
    #pragma unroll
    for (int i = 0; i < 4; ++i)
        #pragma unroll
        for (int j = 0; j < 4; ++j)
            o[i][j] = (f32x4){0.f, 0.f, 0.f, 0.f};

    #pragma unroll 1
    for (int u = 0; u < 4; ++u) {
        f32x4 g0 = {0.f,0.f,0.f,0.f}, g1 = {0.f,0.f,0.f,0.f};
        f32x4 g2 = {0.f,0.f,0.f,0.f}, g3 = {0.f,0.f,0.f,0.f};
        #pragma unroll
        for (int v = 0; v < 4; ++v) {
            const int t = u * 4 + v;
            const char* ap = Alds + (t * 16 + lrow) * 144 + lhi * 16;
            s16x8 a0 = *(const s16x8*)(ap);        // c 0..31 slice
            s16x8 a1 = *(const s16x8*)(ap + 64);   // c 32..63 slice
            const int bidx = (((s * 16 + t) * 2 + 0) * 4 + wid) * 64 + lane;
            s16x8 b0 = wb[bidx];
            s16x8 b1 = wb[bidx + 256];             // ks=1 (+4nt*64)
            f32x4 acc = {0.f, 0.f, 0.f, 0.f};
            acc = __builtin_amdgcn_mfma_f32_16x16x32_bf16(a0, b0, acc, 0, 0, 0);
            acc = __builtin_amdgcn_mfma_f32_16x16x32_bf16(a1, b1, acc, 0, 0, 0);
            // v-transform: g[j] += H4[j][v] * acc   (v static -> signs static)
            g0 += acc;
            if (v == 0) { g1 += acc; g2 += acc; g3 += acc; }
            if (v == 1) { g1 -= acc; g2 += acc; g3 -= acc; }
            if (v == 2) { g1 += acc; g2 -= acc; g3 -= acc; }
            if (v == 3) { g1 -= acc; g2 -= acc; g3 += acc; }
        }
        // u-transform fold: o[i][j] += H4[i][u] * g[j]  (signs wave-uniform)
        const float s1 = (u & 1) ? -1.f : 1.f;
        const float s2 = (u & 2) ? -1.f : 1.f;
        const float s3 = s1 * s2;
        #pragma unroll
        for (int j = 0; j < 4; ++j) {
            f32x4 gj = (j == 0) ? g0 : ((j == 1) ? g1 : ((j == 2) ? g2 : g3));
            o[0][j] += gj;
            o[1][j] += s1 * gj;
            o[2][j] += s2 * gj;
            o[3][j] += s3 * gj;
        }
    }

    // ---------------- epilogue: bias + scatter-store ----------------
    const int k  = wid * 16 + lrow;         // C/D col = lane&15
    const float bk = bias[k];
    const int bimg = bid / 49;              // 49 blocks per image (784/16)
    const int hw0  = (bid % 49) * 16;
    float* __restrict__ outp = out + (s ? (size_t)OUT_STRIDE : 0);

    size_t rbase[4];
    #pragma unroll
    for (int r = 0; r < 4; ++r) {           // C/D row = lhi*4 + r  (pixel)
        int hw = hw0 + lhi * 4 + r;
        int h = hw / 28, w = hw % 28;
        rbase[r] = ((size_t)(bimg * 112 + h * 4) * 112 + (w * 4)) * 64 + k;
    }
    #pragma unroll
    for (int i = 0; i < 4; ++i)
        #pragma unroll
        for (int j = 0; j < 4; ++j) {
            #pragma unroll
            for (int r = 0; r < 4; ++r)
                outp[rbase[r] + (size_t)((i * 112 + j) * 64)] = o[i][j][r] + bk;
        }
}

extern "C" void kernel_launch(void* const* d_in, const int* in_sizes, int n_in,
                              void* d_out, int out_size, void* d_ws, size_t ws_size,
                              hipStream_t stream) {
    const float* t1 = (const float*)d_in[0];
    const float* t2 = (const float*)d_in[1];
    const float* w1 = (const float*)d_in[2];
    const float* w2 = (const float*)d_in[3];
    const float* b1 = (const float*)d_in[4];
    const float* b2 = (const float*)d_in[5];
    unsigned short* wfrag = (unsigned short*)d_ws;   // 2*16*2*4*64*8 bf16 = 256 KB
    float* out = (float*)d_out;

    repack_weights<<<dim3(512), dim3(256), 0, stream>>>(w1, w2, wfrag);
    iwht_main<<<dim3(784, 2), dim3(256), 0, stream>>>(t1, t2, wfrag, b1, b2, out);
}